// Round 6
// baseline (1150.807 us; speedup 1.0000x reference)
//
#include <hip/hip_runtime.h>

// Elman RNN, T=512 B=64 I=256 H=512, fp32 in/out. Two dispatches.
// R11 = R10 + fragment-order (permuted) h layout in LDS.
// R10 post-mortem: LDS still the longest pole (~2100 cyc/step/CU =
// 128 b128 reads @~12cyc + 576 cyc counted bank-conflict). The stride-528
// row-major layout starts lane chunks at only 8 bank-quads.
// R11 stores h so consuming lanes read lane-linearly:
//   addr(batch b, col c) = (c>>4)*256 + b*16 + (c&15)
// Read: ds_read_b128 at kt*1024 + lane*16  -> canonical conflict-free.
// Write: wave w, m-tile m owns slab q=2w+m: dword at q*256+lr*16+4lg
//   (bank 4lr+lg mod 32 = 2-way = free). h0 staging same permutation.
// Pure exact-data permutation -> bit-identical output to R10.
// Kept from R10: wave-rotated K order (rot=(w&3)*2, exact i32), JIT
// {1 DS_READ, 2 MFMA} slots via sched_group_barrier, setprio(1) around
// the MFMA stream, xw register prefetch ping-pong, lgkmcnt-only step
// barrier, int8 W_hh register-resident, 2/ln2 prescale folded into k1.

#define T_LEN 512
#define NBATCH 64
#define ISZ 256
#define HSZ 512

typedef __attribute__((ext_vector_type(8))) short short8;
typedef __attribute__((ext_vector_type(4))) int int4v;
typedef __attribute__((ext_vector_type(4))) float f32x4;

#define LOG2E2f 2.8853900817779268f
#define DEQ2C ((float)(2.8853900817779268 / (127.0 * 127.0 * 22.627416997969522)))

#define SGB __builtin_amdgcn_sched_group_barrier

__device__ __forceinline__ unsigned short f2bf(float f) {
  unsigned u = __float_as_uint(f);
  u += 0x7fffu + ((u >> 16) & 1u);   // RNE
  return (unsigned short)(u >> 16);
}
__device__ __forceinline__ float bf2f(unsigned short h) {
  return __uint_as_float(((unsigned)h) << 16);
}

__device__ __forceinline__ void split_bf(f32x4 a, f32x4 b, short8& hi, short8& lo) {
#pragma unroll
  for (int i = 0; i < 4; ++i) {
    unsigned short h = f2bf(a[i]);
    hi[i] = (short)h;
    lo[i] = (short)f2bf(a[i] - bf2f(h));
    unsigned short h2 = f2bf(b[i]);
    hi[i + 4] = (short)h2;
    lo[i + 4] = (short)f2bf(b[i] - bf2f(h2));
  }
}

// ---------------------------------------------------------------------------
// Kernel 1: input projection (R1-proven). Output pre-scaled by 2/ln2 so k2's
// tanh exponent needs no multiply.
// ---------------------------------------------------------------------------
__global__ __launch_bounds__(512) void xw_proj(
    const float* __restrict__ x, const float* __restrict__ Wih,
    const float* __restrict__ bih, const float* __restrict__ bhh,
    float* __restrict__ out) {
  __shared__ __align__(16) short xhi[16][264];
  __shared__ __align__(16) short xlo[16][264];

  const int tid = threadIdx.x;
  const int w  = tid >> 6;
  const int L  = tid & 63;
  const int lr = L & 15;
  const int lg = L >> 4;

  const int mhalf = blockIdx.x & 1;
  const int grp   = blockIdx.x >> 1;

  short8 Ahi[2][8], Alo[2][8];
  f32x4 bias[2];
  int mt[2];
#pragma unroll
  for (int m = 0; m < 2; ++m) {
    mt[m] = mhalf * 16 + 2 * w + m;
    int j = mt[m] * 16 + lr;
#pragma unroll
    for (int kt = 0; kt < 8; ++kt) {
      int k = kt * 32 + lg * 8;
      const f32x4 v0 = *(const f32x4*)(Wih + j * ISZ + k);
      const f32x4 v1 = *(const f32x4*)(Wih + j * ISZ + k + 4);
      split_bf(v0, v1, Ahi[m][kt], Alo[m][kt]);
    }
    int j0 = mt[m] * 16 + lg * 4;
    f32x4 b1 = *(const f32x4*)(bih + j0);
    f32x4 b2 = *(const f32x4*)(bhh + j0);
    bias[m] = (b1 + b2) * LOG2E2f;
  }

  for (int it = 0; it < 8; ++it) {
    const int tau = grp * 8 + it;
    const int t = tau >> 2;
    const int g = tau & 3;

    __syncthreads();
    {
      const int f   = tid * 8;
      const int row = f >> 8;
      const int i0  = f & 255;
      const float* p = x + ((size_t)(t * NBATCH + g * 16 + row) * ISZ + i0);
      const f32x4 v0 = *(const f32x4*)p;
      const f32x4 v1 = *(const f32x4*)(p + 4);
      short8 hi, lo;
      split_bf(v0, v1, hi, lo);
      *(short8*)(&xhi[row][i0]) = hi;
      *(short8*)(&xlo[row][i0]) = lo;
    }
    __syncthreads();

    f32x4 acc[2];
    acc[0] = f32x4{0.f, 0.f, 0.f, 0.f};
    acc[1] = f32x4{0.f, 0.f, 0.f, 0.f};
#pragma unroll
    for (int kt = 0; kt < 8; ++kt) {
      int koff = kt * 32 + lg * 8;
      short8 bh = *(const short8*)(&xhi[lr][koff]);
      short8 bl = *(const short8*)(&xlo[lr][koff]);
      acc[0] = __builtin_amdgcn_mfma_f32_16x16x32_bf16(Ahi[0][kt], bh, acc[0], 0, 0, 0);
      acc[1] = __builtin_amdgcn_mfma_f32_16x16x32_bf16(Ahi[1][kt], bh, acc[1], 0, 0, 0);
      acc[0] = __builtin_amdgcn_mfma_f32_16x16x32_bf16(Alo[0][kt], bh, acc[0], 0, 0, 0);
      acc[1] = __builtin_amdgcn_mfma_f32_16x16x32_bf16(Alo[1][kt], bh, acc[1], 0, 0, 0);
      acc[0] = __builtin_amdgcn_mfma_f32_16x16x32_bf16(Ahi[0][kt], bl, acc[0], 0, 0, 0);
      acc[1] = __builtin_amdgcn_mfma_f32_16x16x32_bf16(Ahi[1][kt], bl, acc[1], 0, 0, 0);
    }
#pragma unroll
    for (int m = 0; m < 2; ++m) {
      f32x4 r = acc[m] * LOG2E2f + bias[m];
      *(f32x4*)(out + (size_t)((((t * 4 + g) * 32 + mt[m]) * 64) + L) * 4) = r;
    }
  }
}

// ---------------------------------------------------------------------------
// Kernel 2: recurrence. 4 blocks x 1024 threads (16 waves, 4/SIMD).
// Each wave owns 2 m-tiles; K walked in wave-rotated order (exact i32).
// h stored in fragment-order LDS layout (conflict-free lane-linear reads).
// ---------------------------------------------------------------------------
__global__ __launch_bounds__(1024, 4) void rnn_scan_i8(
    const float* __restrict__ Whh, const float* __restrict__ h0,
    float* __restrict__ out) {
  __shared__ __align__(16) char hb[2 * 8192];   // permuted int8 h, dbuf

  const int tid = threadIdx.x;
  const int w  = tid >> 6;    // 0..15
  const int L  = tid & 63;
  const int lr = L & 15;
  const int lg = L >> 4;
  const int g  = blockIdx.x;

  const int rot = (w & 3) << 1;     // 0,2,4,6 — K-rotation per SIMD-mate

  const float QS = 127.0f * 22.627416997969522f;                 // 127*sqrt(512)

  // ---- quantize W_hh: slot j holds fragment kt=(rot+j)&7 (static reg idx)
  int4v A[2][8];
#pragma unroll
  for (int m = 0; m < 2; ++m) {
    const int j = (2 * w + m) * 16 + lr;         // A-row (row-in-tile = lane&15)
#pragma unroll
    for (int jj = 0; jj < 8; ++jj) {
      const int kt = (rot + jj) & 7;
      const float* p = Whh + (size_t)j * HSZ + kt * 64 + lg * 16;  // k=quad*16+i
      int dw[4];
#pragma unroll
      for (int d = 0; d < 4; ++d) {
        f32x4 v = *(const f32x4*)(p + d * 4);
        int pk = 0;
#pragma unroll
        for (int i = 0; i < 4; ++i) {
          float q = __builtin_rintf(fminf(fmaxf(v[i] * QS, -127.f), 127.f));
          pk |= ((int)q & 255) << (8 * i);
        }
        dw[d] = pk;
      }
      A[m][jj] = int4v{dw[0], dw[1], dw[2], dw[3]};
    }
  }

  // ---- stage h0 as int8 into buffer 0, permuted layout (first 512 threads)
  // thread (row=tid>>5, k0=(tid&31)*16) -> 16 contiguous bytes at
  // (k0/16)*256 + row*16  ==  (tid&31)*256 + (tid>>5)*16.
  if (tid < 512) {
    const int row = tid >> 5;           // 0..15
    const int k0  = (tid & 31) * 16;    // 0..496
    const float* p = h0 + ((size_t)(g * 16 + row) * HSZ + k0);
    int dw[4];
#pragma unroll
    for (int c = 0; c < 4; ++c) {
      f32x4 v = *(const f32x4*)(p + c * 4);
      int pk = 0;
#pragma unroll
      for (int i = 0; i < 4; ++i) {
        float q = __builtin_rintf(fminf(fmaxf(v[i] * 127.f, -127.f), 127.f));
        pk |= ((int)q & 255) << (8 * i);
      }
      dw[c] = pk;
    }
    *(int4v*)(&hb[(tid & 31) * 256 + row * 16]) = int4v{dw[0], dw[1], dw[2], dw[3]};
  }
  __syncthreads();

  const int j0 = 32 * w + lg * 4;                        // column base (floats)
  const char* xwp = (const char*)out + ((size_t)(g * 32 + 2 * w) * 64 + L) * 16;
  float* hsp = out + (size_t)(g * 16 + lr) * HSZ + j0;   // slab-0 h_seq base
  const int ldsr = L * 16;                               // lane-linear read base
  const int ldsw = 2 * w * 256 + lr * 16 + lg * 4;       // + m*256 (slab q=2w+m)

  // wave-uniform fragment byte offsets in rotated order (SGPR constants)
  const int ko0 = ((rot + 0) & 7) * 1024;
  const int ko1 = ((rot + 1) & 7) * 1024;
  const int ko2 = ((rot + 2) & 7) * 1024;
  const int ko3 = ((rot + 3) & 7) * 1024;
  const int ko4 = ((rot + 4) & 7) * 1024;
  const int ko5 = ((rot + 5) & 7) * 1024;
  const int ko6 = ((rot + 6) & 7) * 1024;
  const int ko7 = ((rot + 7) & 7) * 1024;

  f32x4 pend[2];
  f32x4 xwA[2], xwB[2];

  // preload xw slab 0 into xwA
#pragma unroll
  for (int m = 0; m < 2; ++m) xwA[m] = *(const f32x4*)(xwp + m * 1024);
  xwp += 131072;

  // one JIT slot: (optional read of slot RJ) + 2 MFMAs of slot J, SGB-pinned
#define SLOT_RD(J, RJ) do {                                                    \
    B##RJ = *(const int4v*)(&hb[cb_ + ldsr + ko##RJ]);                         \
    acc0 = __builtin_amdgcn_mfma_i32_16x16x64_i8(A[0][J], B##J, acc0, 0, 0, 0);\
    acc1 = __builtin_amdgcn_mfma_i32_16x16x64_i8(A[1][J], B##J, acc1, 0, 0, 0);\
    SGB(0x100, 1, 0);  /* 1 DS_READ */                                         \
    SGB(0x8, 2, 0);    /* 2 MFMA    */                                         \
  } while (0)
#define SLOT_NR(J) do {                                                        \
    acc0 = __builtin_amdgcn_mfma_i32_16x16x64_i8(A[0][J], B##J, acc0, 0, 0, 0);\
    acc1 = __builtin_amdgcn_mfma_i32_16x16x64_i8(A[1][J], B##J, acc1, 0, 0, 0);\
    SGB(0x8, 2, 0);    /* 2 MFMA    */                                         \
  } while (0)

  // One step. XWC: xw regs for THIS step (loaded last step). XWN: regs to
  // prefetch NEXT step's xw into. P: LDS read-buffer parity. DOSTORE:
  // write the deferred h_seq slab (t>0).
  // Barrier: lgkmcnt(0)+s_barrier only — vmcnt (prefetch, h_seq stores)
  // intentionally left in flight across it.
#define RNN_STEP(XWC, XWN, P, DOSTORE) do {                                    \
    _Pragma("unroll")                                                          \
    for (int m = 0; m < 2; ++m) XWN[m] = *(const f32x4*)(xwp + m * 1024);      \
    xwp += 131072;                                                             \
    if (DOSTORE) {                                                             \
      _Pragma("unroll")                                                        \
      for (int m = 0; m < 2; ++m) *(f32x4*)(hsp + m * 16) = pend[m];           \
      hsp += NBATCH * HSZ;                                                     \
    }                                                                          \
    const int cb_ = (P) * 8192;                                                \
    int4v B0, B1, B2, B3, B4, B5, B6, B7;                                      \
    /* 3-deep read prologue */                                                 \
    B0 = *(const int4v*)(&hb[cb_ + ldsr + ko0]);                               \
    B1 = *(const int4v*)(&hb[cb_ + ldsr + ko1]);                               \
    B2 = *(const int4v*)(&hb[cb_ + ldsr + ko2]);                               \
    SGB(0x100, 3, 0);                                                          \
    int4v acc0 = int4v{0, 0, 0, 0};                                            \
    int4v acc1 = int4v{0, 0, 0, 0};                                            \
    __builtin_amdgcn_s_setprio(1);                                             \
    SLOT_RD(0, 3);                                                             \
    SLOT_RD(1, 4);                                                             \
    SLOT_RD(2, 5);                                                             \
    SLOT_RD(3, 6);                                                             \
    SLOT_RD(4, 7);                                                             \
    SLOT_NR(5);                                                                \
    SLOT_NR(6);                                                                \
    SLOT_NR(7);                                                                \
    __builtin_amdgcn_s_setprio(0);                                             \
    _Pragma("unroll")                                                          \
    for (int m = 0; m < 2; ++m) {                                              \
      unsigned qi[4];                                                          \
      f32x4 hh;                                                                \
      const int4v am = m ? acc1 : acc0;                                        \
      _Pragma("unroll")                                                        \
      for (int r = 0; r < 4; ++r) {                                            \
        float y2 = fmaf((float)am[r], DEQ2C, XWC[m][r]);                       \
        float e  = __builtin_amdgcn_exp2f(y2);        /* e^{2y} */             \
        float rc = __builtin_amdgcn_rcpf(1.0f + e);                            \
        float hv = fmaf(-2.0f, rc, 1.0f);             /* tanh(y) */            \
        hh[r] = hv;                                                            \
        qi[r] = __float_as_uint(fmaf(hv, 127.0f, 12582912.0f));                \
      }                                                                        \
      pend[m] = hh;                                                            \
      unsigned pp0 = __builtin_amdgcn_perm(qi[1], qi[0], 0x0c0c0400u);         \
      unsigned pp1 = __builtin_amdgcn_perm(qi[3], qi[2], 0x04000c0cu);         \
      *(unsigned*)(&hb[(1 - (P)) * 8192 + ldsw + m * 256]) = pp0 | pp1;        \
    }                                                                          \
    asm volatile("s_waitcnt lgkmcnt(0)\n\ts_barrier" ::: "memory");            \
  } while (0)

  RNN_STEP(xwA, xwB, 0, 0);                 // t = 0 (reads h0 in buffer 0)
  for (int it = 0; it < 255; ++it) {
    RNN_STEP(xwB, xwA, 1, 1);               // odd t
    RNN_STEP(xwA, xwB, 0, 1);               // even t
  }
  RNN_STEP(xwB, xwA, 1, 1);                 // t = 511 (prefetch reads h_last
                                            // region: in-bounds, unconsumed)
#undef RNN_STEP
#undef SLOT_RD
#undef SLOT_NR

  // epilogue: h_seq[T-1] and h_last
#pragma unroll
  for (int m = 0; m < 2; ++m) {
    *(f32x4*)(hsp + m * 16) = pend[m];
    *(f32x4*)(out + (size_t)T_LEN * NBATCH * HSZ +
              (size_t)(g * 16 + lr) * HSZ + j0 + m * 16) = pend[m];
  }
}

extern "C" void kernel_launch(void* const* d_in, const int* in_sizes, int n_in,
                              void* d_out, int out_size, void* d_ws, size_t ws_size,
                              hipStream_t stream) {
  const float* x   = (const float*)d_in[0];
  const float* h0  = (const float*)d_in[1];
  const float* Wih = (const float*)d_in[2];
  const float* Whh = (const float*)d_in[3];
  const float* bih = (const float*)d_in[4];
  const float* bhh = (const float*)d_in[5];
  float* out = (float*)d_out;

  xw_proj<<<512, 512, 0, stream>>>(x, Wih, bih, bhh, out);
  rnn_scan_i8<<<4, 1024, 0, stream>>>(Whh, h0, out);
}

// Round 7
// 825.115 us; speedup vs baseline: 1.3947x; 1.3947x over previous
//
#include <hip/hip_runtime.h>

// Elman RNN, T=512 B=64 I=256 H=512, fp32 in/out. Two dispatches.
// R12 = R10 (proven best: 699 us k2) + packed-f32 epilogue.
// R11 post-mortem: conflict-free LDS layout collapsed SQ_LDS_BANK_CONFLICT
// 9x yet cost +45% — R10's conflicts were hidden, and the lane-linear
// layout added ~1500 cyc/step of unidentified LDS serialization. Layout
// REVERTED to R10's 528-stride (do not touch again).
// R10 pole accounting: VALU ~2400 cyc/step/CU is the largest pole (LDS
// ~2100, MFMA ~1575). R12 cuts VALU count: epilogue processed in elem
// PAIRS with float2 vector math -> v_pk_fma_f32 / v_pk_add_f32 (VOP3P,
// both halves in one issue). 14 -> 10 instr per pair; exp2/rcp/cvt stay
// scalar. __builtin_elementwise_fma is bit-identical per component ->
// output unchanged (absmax 0.009765625).
// Kept from R10: wave-rotated K order (rot=(w&3)*2, exact i32), JIT
// {1 DS_READ, 2 MFMA} slots via sched_group_barrier, setprio(1) around
// the MFMA stream, xw register prefetch ping-pong, lgkmcnt-only step
// barrier, int8 W_hh register-resident, int8 h dbuf LDS stride 528,
// 2/ln2 prescale folded into k1.

#define T_LEN 512
#define NBATCH 64
#define ISZ 256
#define HSZ 512

typedef __attribute__((ext_vector_type(8))) short short8;
typedef __attribute__((ext_vector_type(4))) int int4v;
typedef __attribute__((ext_vector_type(4))) float f32x4;
typedef __attribute__((ext_vector_type(2))) float f32x2;

#define LOG2E2f 2.8853900817779268f
#define DEQ2C ((float)(2.8853900817779268 / (127.0 * 127.0 * 22.627416997969522)))

#define SGB __builtin_amdgcn_sched_group_barrier

__device__ __forceinline__ unsigned short f2bf(float f) {
  unsigned u = __float_as_uint(f);
  u += 0x7fffu + ((u >> 16) & 1u);   // RNE
  return (unsigned short)(u >> 16);
}
__device__ __forceinline__ float bf2f(unsigned short h) {
  return __uint_as_float(((unsigned)h) << 16);
}

__device__ __forceinline__ void split_bf(f32x4 a, f32x4 b, short8& hi, short8& lo) {
#pragma unroll
  for (int i = 0; i < 4; ++i) {
    unsigned short h = f2bf(a[i]);
    hi[i] = (short)h;
    lo[i] = (short)f2bf(a[i] - bf2f(h));
    unsigned short h2 = f2bf(b[i]);
    hi[i + 4] = (short)h2;
    lo[i + 4] = (short)f2bf(b[i] - bf2f(h2));
  }
}

// ---------------------------------------------------------------------------
// Kernel 1: input projection (R1-proven). Output pre-scaled by 2/ln2 so k2's
// tanh exponent needs no multiply.
// ---------------------------------------------------------------------------
__global__ __launch_bounds__(512) void xw_proj(
    const float* __restrict__ x, const float* __restrict__ Wih,
    const float* __restrict__ bih, const float* __restrict__ bhh,
    float* __restrict__ out) {
  __shared__ __align__(16) short xhi[16][264];
  __shared__ __align__(16) short xlo[16][264];

  const int tid = threadIdx.x;
  const int w  = tid >> 6;
  const int L  = tid & 63;
  const int lr = L & 15;
  const int lg = L >> 4;

  const int mhalf = blockIdx.x & 1;
  const int grp   = blockIdx.x >> 1;

  short8 Ahi[2][8], Alo[2][8];
  f32x4 bias[2];
  int mt[2];
#pragma unroll
  for (int m = 0; m < 2; ++m) {
    mt[m] = mhalf * 16 + 2 * w + m;
    int j = mt[m] * 16 + lr;
#pragma unroll
    for (int kt = 0; kt < 8; ++kt) {
      int k = kt * 32 + lg * 8;
      const f32x4 v0 = *(const f32x4*)(Wih + j * ISZ + k);
      const f32x4 v1 = *(const f32x4*)(Wih + j * ISZ + k + 4);
      split_bf(v0, v1, Ahi[m][kt], Alo[m][kt]);
    }
    int j0 = mt[m] * 16 + lg * 4;
    f32x4 b1 = *(const f32x4*)(bih + j0);
    f32x4 b2 = *(const f32x4*)(bhh + j0);
    bias[m] = (b1 + b2) * LOG2E2f;
  }

  for (int it = 0; it < 8; ++it) {
    const int tau = grp * 8 + it;
    const int t = tau >> 2;
    const int g = tau & 3;

    __syncthreads();
    {
      const int f   = tid * 8;
      const int row = f >> 8;
      const int i0  = f & 255;
      const float* p = x + ((size_t)(t * NBATCH + g * 16 + row) * ISZ + i0);
      const f32x4 v0 = *(const f32x4*)p;
      const f32x4 v1 = *(const f32x4*)(p + 4);
      short8 hi, lo;
      split_bf(v0, v1, hi, lo);
      *(short8*)(&xhi[row][i0]) = hi;
      *(short8*)(&xlo[row][i0]) = lo;
    }
    __syncthreads();

    f32x4 acc[2];
    acc[0] = f32x4{0.f, 0.f, 0.f, 0.f};
    acc[1] = f32x4{0.f, 0.f, 0.f, 0.f};
#pragma unroll
    for (int kt = 0; kt < 8; ++kt) {
      int koff = kt * 32 + lg * 8;
      short8 bh = *(const short8*)(&xhi[lr][koff]);
      short8 bl = *(const short8*)(&xlo[lr][koff]);
      acc[0] = __builtin_amdgcn_mfma_f32_16x16x32_bf16(Ahi[0][kt], bh, acc[0], 0, 0, 0);
      acc[1] = __builtin_amdgcn_mfma_f32_16x16x32_bf16(Ahi[1][kt], bh, acc[1], 0, 0, 0);
      acc[0] = __builtin_amdgcn_mfma_f32_16x16x32_bf16(Alo[0][kt], bh, acc[0], 0, 0, 0);
      acc[1] = __builtin_amdgcn_mfma_f32_16x16x32_bf16(Alo[1][kt], bh, acc[1], 0, 0, 0);
      acc[0] = __builtin_amdgcn_mfma_f32_16x16x32_bf16(Ahi[0][kt], bl, acc[0], 0, 0, 0);
      acc[1] = __builtin_amdgcn_mfma_f32_16x16x32_bf16(Ahi[1][kt], bl, acc[1], 0, 0, 0);
    }
#pragma unroll
    for (int m = 0; m < 2; ++m) {
      f32x4 r = acc[m] * LOG2E2f + bias[m];
      *(f32x4*)(out + (size_t)((((t * 4 + g) * 32 + mt[m]) * 64) + L) * 4) = r;
    }
  }
}

// ---------------------------------------------------------------------------
// Kernel 2: recurrence. 4 blocks x 1024 threads (16 waves, 4/SIMD).
// Each wave owns 2 m-tiles; K walked in wave-rotated order (exact i32).
// ---------------------------------------------------------------------------
__global__ __launch_bounds__(1024, 4) void rnn_scan_i8(
    const float* __restrict__ Whh, const float* __restrict__ h0,
    float* __restrict__ out) {
  __shared__ __align__(16) char hb[2 * 16 * 528];

  const int tid = threadIdx.x;
  const int w  = tid >> 6;    // 0..15
  const int L  = tid & 63;
  const int lr = L & 15;
  const int lg = L >> 4;
  const int g  = blockIdx.x;

  const int rot = (w & 3) << 1;     // 0,2,4,6 — K-rotation per SIMD-mate

  const float QS = 127.0f * 22.627416997969522f;                 // 127*sqrt(512)

  // ---- quantize W_hh: slot j holds fragment kt=(rot+j)&7 (static reg idx)
  int4v A[2][8];
#pragma unroll
  for (int m = 0; m < 2; ++m) {
    const int j = (2 * w + m) * 16 + lr;         // A-row (row-in-tile = lane&15)
#pragma unroll
    for (int jj = 0; jj < 8; ++jj) {
      const int kt = (rot + jj) & 7;
      const float* p = Whh + (size_t)j * HSZ + kt * 64 + lg * 16;  // k=quad*16+i
      int dw[4];
#pragma unroll
      for (int d = 0; d < 4; ++d) {
        f32x4 v = *(const f32x4*)(p + d * 4);
        int pk = 0;
#pragma unroll
        for (int i = 0; i < 4; ++i) {
          float q = __builtin_rintf(fminf(fmaxf(v[i] * QS, -127.f), 127.f));
          pk |= ((int)q & 255) << (8 * i);
        }
        dw[d] = pk;
      }
      A[m][jj] = int4v{dw[0], dw[1], dw[2], dw[3]};
    }
  }

  // ---- stage h0 as int8 into buffer 0: 16 rows x 512 (first 512 threads)
  if (tid < 512) {
    const int row = tid >> 5;           // 0..15
    const int k0  = (tid & 31) * 16;    // 0..496
    const float* p = h0 + ((size_t)(g * 16 + row) * HSZ + k0);
    int dw[4];
#pragma unroll
    for (int c = 0; c < 4; ++c) {
      f32x4 v = *(const f32x4*)(p + c * 4);
      int pk = 0;
#pragma unroll
      for (int i = 0; i < 4; ++i) {
        float q = __builtin_rintf(fminf(fmaxf(v[i] * 127.f, -127.f), 127.f));
        pk |= ((int)q & 255) << (8 * i);
      }
      dw[c] = pk;
    }
    *(int4v*)(&hb[row * 528 + k0]) = int4v{dw[0], dw[1], dw[2], dw[3]};
  }
  __syncthreads();

  const int j0 = 32 * w + lg * 4;                        // column base (floats)
  const char* xwp = (const char*)out + ((size_t)(g * 32 + 2 * w) * 64 + L) * 16;
  float* hsp = out + (size_t)(g * 16 + lr) * HSZ + j0;   // slab-0 h_seq base
  const int ldsr = lr * 528 + lg * 16;
  const int ldsw = lr * 528 + j0;

  // wave-uniform fragment byte offsets in rotated order (SGPR constants)
  const int ko0 = ((rot + 0) & 7) * 64;
  const int ko1 = ((rot + 1) & 7) * 64;
  const int ko2 = ((rot + 2) & 7) * 64;
  const int ko3 = ((rot + 3) & 7) * 64;
  const int ko4 = ((rot + 4) & 7) * 64;
  const int ko5 = ((rot + 5) & 7) * 64;
  const int ko6 = ((rot + 6) & 7) * 64;
  const int ko7 = ((rot + 7) & 7) * 64;

  f32x4 pend[2];
  f32x4 xwA[2], xwB[2];

  // preload xw slab 0 into xwA
#pragma unroll
  for (int m = 0; m < 2; ++m) xwA[m] = *(const f32x4*)(xwp + m * 1024);
  xwp += 131072;

  // one JIT slot: (optional read of slot RJ) + 2 MFMAs of slot J, SGB-pinned
#define SLOT_RD(J, RJ) do {                                                    \
    B##RJ = *(const int4v*)(&hb[cb_ + ldsr + ko##RJ]);                         \
    acc0 = __builtin_amdgcn_mfma_i32_16x16x64_i8(A[0][J], B##J, acc0, 0, 0, 0);\
    acc1 = __builtin_amdgcn_mfma_i32_16x16x64_i8(A[1][J], B##J, acc1, 0, 0, 0);\
    SGB(0x100, 1, 0);  /* 1 DS_READ */                                         \
    SGB(0x8, 2, 0);    /* 2 MFMA    */                                         \
  } while (0)
#define SLOT_NR(J) do {                                                        \
    acc0 = __builtin_amdgcn_mfma_i32_16x16x64_i8(A[0][J], B##J, acc0, 0, 0, 0);\
    acc1 = __builtin_amdgcn_mfma_i32_16x16x64_i8(A[1][J], B##J, acc1, 0, 0, 0);\
    SGB(0x8, 2, 0);    /* 2 MFMA    */                                         \
  } while (0)

  // packed epilogue for one elem pair (R0,R0+1) of tile m:
  // pk_fma dequant -> scalar exp2 -> pk_add -> scalar rcp -> pk_fma tanh
  // -> pk_fma magic-quant. Bit-identical per component to the scalar form.
#define EP_PAIR(AM, XWM, R0, HVD, QA, QB) do {                                 \
    f32x2 a_  = f32x2{(float)AM[R0], (float)AM[(R0) + 1]};                     \
    f32x2 x_  = f32x2{XWM[R0], XWM[(R0) + 1]};                                 \
    f32x2 y_  = __builtin_elementwise_fma(a_, f32x2{DEQ2C, DEQ2C}, x_);        \
    float e0_ = __builtin_amdgcn_exp2f(y_[0]);                                 \
    float e1_ = __builtin_amdgcn_exp2f(y_[1]);                                 \
    f32x2 d_  = f32x2{e0_, e1_} + 1.0f;                                        \
    f32x2 rc_ = f32x2{__builtin_amdgcn_rcpf(d_[0]),                            \
                      __builtin_amdgcn_rcpf(d_[1])};                           \
    f32x2 hv_ = __builtin_elementwise_fma(rc_, f32x2{-2.f, -2.f},              \
                                          f32x2{1.f, 1.f});                    \
    f32x2 q_  = __builtin_elementwise_fma(hv_, f32x2{127.f, 127.f},            \
                                          f32x2{12582912.f, 12582912.f});      \
    HVD = hv_;                                                                 \
    QA = __float_as_uint(q_[0]);                                               \
    QB = __float_as_uint(q_[1]);                                               \
  } while (0)

  // One step. XWC: xw regs for THIS step (loaded last step). XWN: regs to
  // prefetch NEXT step's xw into. P: LDS read-buffer parity. DOSTORE:
  // write the deferred h_seq slab (t>0).
  // Barrier: lgkmcnt(0)+s_barrier only — vmcnt (prefetch, h_seq stores)
  // intentionally left in flight across it.
#define RNN_STEP(XWC, XWN, P, DOSTORE) do {                                    \
    _Pragma("unroll")                                                          \
    for (int m = 0; m < 2; ++m) XWN[m] = *(const f32x4*)(xwp + m * 1024);      \
    xwp += 131072;                                                             \
    if (DOSTORE) {                                                             \
      _Pragma("unroll")                                                        \
      for (int m = 0; m < 2; ++m) *(f32x4*)(hsp + m * 16) = pend[m];           \
      hsp += NBATCH * HSZ;                                                     \
    }                                                                          \
    const int cb_ = (P) * 8448;                                                \
    int4v B0, B1, B2, B3, B4, B5, B6, B7;                                      \
    /* 3-deep read prologue */                                                 \
    B0 = *(const int4v*)(&hb[cb_ + ldsr + ko0]);                               \
    B1 = *(const int4v*)(&hb[cb_ + ldsr + ko1]);                               \
    B2 = *(const int4v*)(&hb[cb_ + ldsr + ko2]);                               \
    SGB(0x100, 3, 0);                                                          \
    int4v acc0 = int4v{0, 0, 0, 0};                                            \
    int4v acc1 = int4v{0, 0, 0, 0};                                            \
    __builtin_amdgcn_s_setprio(1);                                             \
    SLOT_RD(0, 3);                                                             \
    SLOT_RD(1, 4);                                                             \
    SLOT_RD(2, 5);                                                             \
    SLOT_RD(3, 6);                                                             \
    SLOT_RD(4, 7);                                                             \
    SLOT_NR(5);                                                                \
    SLOT_NR(6);                                                                \
    SLOT_NR(7);                                                                \
    __builtin_amdgcn_s_setprio(0);                                             \
    _Pragma("unroll")                                                          \
    for (int m = 0; m < 2; ++m) {                                              \
      const int4v am = m ? acc1 : acc0;                                        \
      unsigned q0_, q1_, q2_, q3_;                                             \
      f32x2 hv01_, hv23_;                                                      \
      EP_PAIR(am, XWC[m], 0, hv01_, q0_, q1_);                                 \
      EP_PAIR(am, XWC[m], 2, hv23_, q2_, q3_);                                 \
      pend[m] = f32x4{hv01_[0], hv01_[1], hv23_[0], hv23_[1]};                 \
      unsigned pp0 = __builtin_amdgcn_perm(q1_, q0_, 0x0c0c0400u);             \
      unsigned pp1 = __builtin_amdgcn_perm(q3_, q2_, 0x04000c0cu);             \
      *(unsigned*)(&hb[(1 - (P)) * 8448 + ldsw + m * 16]) = pp0 | pp1;         \
    }                                                                          \
    asm volatile("s_waitcnt lgkmcnt(0)\n\ts_barrier" ::: "memory");            \
  } while (0)

  RNN_STEP(xwA, xwB, 0, 0);                 // t = 0 (reads h0 in buffer 0)
  for (int it = 0; it < 255; ++it) {
    RNN_STEP(xwB, xwA, 1, 1);               // odd t
    RNN_STEP(xwA, xwB, 0, 1);               // even t
  }
  RNN_STEP(xwB, xwA, 1, 1);                 // t = 511 (prefetch reads h_last
                                            // region: in-bounds, unconsumed)
#undef RNN_STEP
#undef EP_PAIR
#undef SLOT_RD
#undef SLOT_NR

  // epilogue: h_seq[T-1] and h_last
#pragma unroll
  for (int m = 0; m < 2; ++m) {
    *(f32x4*)(hsp + m * 16) = pend[m];
    *(f32x4*)(out + (size_t)T_LEN * NBATCH * HSZ +
              (size_t)(g * 16 + lr) * HSZ + j0 + m * 16) = pend[m];
  }
}

extern "C" void kernel_launch(void* const* d_in, const int* in_sizes, int n_in,
                              void* d_out, int out_size, void* d_ws, size_t ws_size,
                              hipStream_t stream) {
  const float* x   = (const float*)d_in[0];
  const float* h0  = (const float*)d_in[1];
  const float* Wih = (const float*)d_in[2];
  const float* Whh = (const float*)d_in[3];
  const float* bih = (const float*)d_in[4];
  const float* bhh = (const float*)d_in[5];
  float* out = (float*)d_out;

  xw_proj<<<512, 512, 0, stream>>>(x, Wih, bih, bhh, out);
  rnn_scan_i8<<<4, 1024, 0, stream>>>(Whh, h0, out);
}